// Round 3
// baseline (208.144 us; speedup 1.0000x reference)
//
#include <hip/hip_runtime.h>

#define TPB 256

// ---------------------------------------------------------------------------
// partial_activation: Y[32] viewed as 16 blocks of 2, M=2, Q=2.0.
// pos[b] = #(Y[2b..2b+1] > 0); minI/maxI = FIRST argmin/argmax of pos;
// mask: *2 on max block if pos==2, *0 on min block if pos==0.
// train += relu-sum of min block (if min fails) + (-negsum) of max block (if max fails).
// succ += (min_succ && max_succ).
// All indexing is compile-time constant (cndmask chains) so Y stays in VGPRs
// (rule #20: runtime-indexed arrays spill to scratch).
// IDENTICAL math/order to the round-2 kernel that passed (absmax 0.0039).
// ---------------------------------------------------------------------------
__device__ __forceinline__ void partial_act(float (&Y)[32], float& t_acc, int& s_cnt)
{
    int pos[16];
#pragma unroll
    for (int b = 0; b < 16; ++b)
        pos[b] = (Y[2 * b] > 0.0f ? 1 : 0) + (Y[2 * b + 1] > 0.0f ? 1 : 0);

    int minv = pos[0], maxv = pos[0];
    int minI = 0, maxI = 0;
    float ymin0 = Y[0], ymin1 = Y[1];
    float ymax0 = Y[0], ymax1 = Y[1];
#pragma unroll
    for (int b = 1; b < 16; ++b) {
        bool lt = pos[b] < minv;   // strict < keeps FIRST argmin (matches jnp.argmin)
        minv  = lt ? pos[b]       : minv;
        minI  = lt ? b            : minI;
        ymin0 = lt ? Y[2 * b]     : ymin0;
        ymin1 = lt ? Y[2 * b + 1] : ymin1;
        bool gt = pos[b] > maxv;   // strict > keeps FIRST argmax (matches jnp.argmax)
        maxv  = gt ? pos[b]       : maxv;
        maxI  = gt ? b            : maxI;
        ymax0 = gt ? Y[2 * b]     : ymax0;
        ymax1 = gt ? Y[2 * b + 1] : ymax1;
    }
    bool min_succ = (minv == 0);
    bool max_succ = (maxv == 2);

    // train terms use PRE-mask Y values: y*(y>0) == max(y,0); -y*(y<0) == -min(y,0)
    float cmin = fmaxf(ymin0, 0.0f) + fmaxf(ymin1, 0.0f);
    float cmax = -(fminf(ymax0, 0.0f) + fminf(ymax1, 0.0f));
    t_acc += (min_succ ? 0.0f : cmin) + (max_succ ? 0.0f : cmax);
    s_cnt += (min_succ && max_succ) ? 1 : 0;

    // apply mask (whole 2-element block since M == BLOCK == 2)
#pragma unroll
    for (int b = 0; b < 16; ++b) {
        bool ismax = max_succ && (b == maxI);
        bool ismin = min_succ && (b == minI);
        float mfac = ismax ? 2.0f : 1.0f;
        mfac = ismin ? 0.0f : mfac;
        Y[2 * b]     *= mfac;
        Y[2 * b + 1] *= mfac;
    }
}

// ---------------------------------------------------------------------------
// Main kernel: one thread per row. Round-3 change: weights staged in LDS and
// read with wave-uniform BROADCAST ds_read_b128 (conflict-free, dedicated LDS
// pipe) instead of 1000+ s_loads on the single per-CU scalar unit. Layer 2 is
// k-outer over a TRANSPOSED W2 so each k-step reads one contiguous column
// (8x ds_read_b128) and issues 32 independent fma (dep distance 32 -> ILP).
// Each Z[j] chain remains ascending-k -> bit-identical to round-2 kernel.
// ---------------------------------------------------------------------------
__global__ __launch_bounds__(TPB, 4) void net_main(
    const float* __restrict__ x,
    const float* __restrict__ W1, const float* __restrict__ b1,
    const float* __restrict__ W2, const float* __restrict__ b2,
    const float* __restrict__ W3, const float* __restrict__ b3,
    float* __restrict__ out,
    float* __restrict__ t_part, int* __restrict__ c_part,
    unsigned* __restrict__ counter,
    int nrows, double inv_denom)
{
    __shared__ float sW1[64];     // [j][0..1] row-major, 16B-aligned
    __shared__ float sB1[32];
    __shared__ float sW2T[1024];  // TRANSPOSED: sW2T[k*32+j] = W2[j*32+k]
    __shared__ float sB2[32];
    __shared__ float sW3[64];     // row-major [2][32]
    __shared__ float sB3[2];

    const int tid = threadIdx.x;

    // ---- stage weights into LDS (one-time per block, ~5 KB) ----
    if (tid < 64)        sW1[tid]       = W1[tid];
    else if (tid < 96)   sB1[tid - 64]  = b1[tid - 64];
    else if (tid < 160)  sW3[tid - 96]  = W3[tid - 96];
    else if (tid < 192)  sB2[tid - 160] = b2[tid - 160];
    else if (tid < 194)  sB3[tid - 192] = b3[tid - 192];
#pragma unroll
    for (int i = tid; i < 1024; i += TPB) {
        int j = i >> 5, k = i & 31;          // coalesced global read of W2 row j
        sW2T[k * 32 + j] = W2[i];            // transposed LDS write (one-time)
    }
    __syncthreads();

    const int row = blockIdx.x * TPB + tid;

    float t_acc = 0.0f;
    int   s_cnt = 0;

    if (row < nrows) {
        const float2 xv = reinterpret_cast<const float2*>(x)[row];

        // ---- layer 1: Y = x @ W1^T + b1 (same fma order as round 2) ----
        float Y[32];
#pragma unroll
        for (int p = 0; p < 16; ++p) {
            float4 w = reinterpret_cast<const float4*>(sW1)[p]; // rows 2p,2p+1
            Y[2 * p]     = fmaf(xv.y, w.y, fmaf(xv.x, w.x, sB1[2 * p]));
            Y[2 * p + 1] = fmaf(xv.y, w.w, fmaf(xv.x, w.z, sB1[2 * p + 1]));
        }

        partial_act(Y, t_acc, s_cnt);

        // ---- layer 2: Z = Y @ W2^T + b2, k-outer over transposed W2 ----
        float Z[32];
#pragma unroll
        for (int p = 0; p < 8; ++p) {
            float4 bz = reinterpret_cast<const float4*>(sB2)[p];
            Z[4 * p] = bz.x; Z[4 * p + 1] = bz.y; Z[4 * p + 2] = bz.z; Z[4 * p + 3] = bz.w;
        }
#pragma unroll
        for (int k = 0; k < 32; ++k) {
            const float4* col = reinterpret_cast<const float4*>(&sW2T[k * 32]);
            const float yk = Y[k];
#pragma unroll
            for (int q = 0; q < 8; ++q) {
                float4 w = col[q];           // broadcast ds_read_b128
                Z[4 * q]     = fmaf(yk, w.x, Z[4 * q]);
                Z[4 * q + 1] = fmaf(yk, w.y, Z[4 * q + 1]);
                Z[4 * q + 2] = fmaf(yk, w.z, Z[4 * q + 2]);
                Z[4 * q + 3] = fmaf(yk, w.w, Z[4 * q + 3]);
            }
        }

        partial_act(Z, t_acc, s_cnt);

        // ---- layer 3 + softmax over 2 logits (same order as round 2) ----
        float z0 = sB3[0], z1 = sB3[1];
#pragma unroll
        for (int k = 0; k < 32; ++k) {
            z0 = fmaf(Z[k], sW3[k], z0);
            z1 = fmaf(Z[k], sW3[32 + k], z1);
        }
        float m  = fmaxf(z0, z1);
        float e0 = __expf(z0 - m);
        float e1 = __expf(z1 - m);
        float inv = 1.0f / (e0 + e1);
        float2 o;
        o.x = e0 * inv;
        o.y = e1 * inv;
        reinterpret_cast<float2*>(out)[row] = o;
    }

    // ---- block reduction: wave shuffle -> LDS -> per-block partial store ----
#pragma unroll
    for (int off = 32; off; off >>= 1) {
        t_acc += __shfl_down(t_acc, off);
        s_cnt += __shfl_down(s_cnt, off);
    }
    __shared__ float ts[TPB / 64];
    __shared__ int   cs[TPB / 64];
    __shared__ bool  amLast;
    const int wid  = tid >> 6;
    const int lane = tid & 63;
    if (lane == 0) { ts[wid] = t_acc; cs[wid] = s_cnt; }
    __syncthreads();
    if (tid == 0) {
        float tt = ts[0];
        int   cc = cs[0];
#pragma unroll
        for (int w = 1; w < TPB / 64; ++w) { tt += ts[w]; cc += cs[w]; }
        t_part[blockIdx.x] = tt;
        c_part[blockIdx.x] = cc;
        __threadfence();                               // partials visible device-wide
        unsigned old = atomicAdd(counter, 1u);         // device-scope by default
        amLast = (old == gridDim.x - 1);
    }
    __syncthreads();

    // ---- last block reduces all partials (fixed order -> deterministic) ----
    if (amLast) {
        __threadfence();                               // acquire other blocks' stores
        double t = 0.0;
        int    c = 0;
        const int nparts = gridDim.x;
        for (int i = tid; i < nparts; i += TPB) {
            t += (double)t_part[i];
            c += c_part[i];
        }
#pragma unroll
        for (int off = 32; off; off >>= 1) {
            t += __shfl_down(t, off);
            c += __shfl_down(c, off);
        }
        __shared__ double td[TPB / 64];
        __shared__ int    cd[TPB / 64];
        if (lane == 0) { td[wid] = t; cd[wid] = c; }
        __syncthreads();
        if (tid == 0) {
            double tt = 0.0;
            int    cc = 0;
#pragma unroll
            for (int w = 0; w < TPB / 64; ++w) { tt += td[w]; cc += cd[w]; }
            float* scal = out + (size_t)nrows * 2;
            scal[0] = (float)((double)cc * inv_denom); // succ = cnt / (2B)
            scal[1] = (float)tt;                       // train = t1 + t2
        }
    }
}

extern "C" void kernel_launch(void* const* d_in, const int* in_sizes, int n_in,
                              void* d_out, int out_size, void* d_ws, size_t ws_size,
                              hipStream_t stream)
{
    const float* x  = (const float*)d_in[0];
    const float* W1 = (const float*)d_in[1];
    const float* b1 = (const float*)d_in[2];
    const float* W2 = (const float*)d_in[3];
    const float* b2 = (const float*)d_in[4];
    const float* W3 = (const float*)d_in[5];
    const float* b3 = (const float*)d_in[6];
    float* out = (float*)d_out;

    const int nrows   = in_sizes[0] / 2;          // B = 1048576
    const int nblocks = (nrows + TPB - 1) / TPB;  // 4096

    float*    t_part  = (float*)d_ws;
    int*      c_part  = (int*)((char*)d_ws + (size_t)nblocks * sizeof(float));
    unsigned* counter = (unsigned*)((char*)d_ws + (size_t)nblocks * 2 * sizeof(float));

    // ws is poisoned 0xAA before every timed launch -> zero the done-counter.
    hipMemsetAsync(counter, 0, sizeof(unsigned), stream);

    net_main<<<nblocks, TPB, 0, stream>>>(x, W1, b1, W2, b2, W3, b3,
                                          out, t_part, c_part, counter,
                                          nrows, 1.0 / (2.0 * (double)nrows));
}

// Round 6
// 147.499 us; speedup vs baseline: 1.4112x; 1.4112x over previous
//
#include <hip/hip_runtime.h>

#define TPB 256

// ---------------------------------------------------------------------------
// partial_activation: Y[32] viewed as 16 blocks of 2, M=2, Q=2.0.
// pos[b] = #(Y[2b..2b+1] > 0); minI/maxI = FIRST argmin/argmax of pos;
// mask: *2 on max block if pos==2, *0 on min block if pos==0.
// train += relu-sum of min block (if fails) + (-negsum) of max block (if fails).
// succ += (min_succ && max_succ).
// All indexing compile-time constant (rule #20) -> Y stays in VGPRs.
// IDENTICAL math/order to round-2/3 kernels that passed (absmax 0.0039) --
// do NOT reassociate: mask decisions are sign-sensitive.
// ---------------------------------------------------------------------------
__device__ __forceinline__ void partial_act(float (&Y)[32], float& t_acc, int& s_cnt)
{
    int pos[16];
#pragma unroll
    for (int b = 0; b < 16; ++b)
        pos[b] = (Y[2 * b] > 0.0f ? 1 : 0) + (Y[2 * b + 1] > 0.0f ? 1 : 0);

    int minv = pos[0], maxv = pos[0];
    int minI = 0, maxI = 0;
    float ymin0 = Y[0], ymin1 = Y[1];
    float ymax0 = Y[0], ymax1 = Y[1];
#pragma unroll
    for (int b = 1; b < 16; ++b) {
        bool lt = pos[b] < minv;   // strict < keeps FIRST argmin (jnp.argmin)
        minv  = lt ? pos[b]       : minv;
        minI  = lt ? b            : minI;
        ymin0 = lt ? Y[2 * b]     : ymin0;
        ymin1 = lt ? Y[2 * b + 1] : ymin1;
        bool gt = pos[b] > maxv;   // strict > keeps FIRST argmax (jnp.argmax)
        maxv  = gt ? pos[b]       : maxv;
        maxI  = gt ? b            : maxI;
        ymax0 = gt ? Y[2 * b]     : ymax0;
        ymax1 = gt ? Y[2 * b + 1] : ymax1;
    }
    bool min_succ = (minv == 0);
    bool max_succ = (maxv == 2);

    // train uses PRE-mask Y: y*(y>0)==max(y,0); -y*(y<0)==-min(y,0)
    float cmin = fmaxf(ymin0, 0.0f) + fmaxf(ymin1, 0.0f);
    float cmax = -(fminf(ymax0, 0.0f) + fminf(ymax1, 0.0f));
    t_acc += (min_succ ? 0.0f : cmin) + (max_succ ? 0.0f : cmax);
    s_cnt += (min_succ && max_succ) ? 1 : 0;

#pragma unroll
    for (int b = 0; b < 16; ++b) {
        bool ismax = max_succ && (b == maxI);
        bool ismin = min_succ && (b == minI);
        float mfac = ismax ? 2.0f : 1.0f;
        mfac = ismin ? 0.0f : mfac;
        Y[2 * b]     *= mfac;
        Y[2 * b + 1] *= mfac;
    }
}

// ---------------------------------------------------------------------------
// Round-4 structure (resubmitted again -- broker timeouts, never measured):
// TWO rows per thread (r0, r0+half), j-outer layer 2. Weights are wave-uniform
// reads with constant offsets -> compiler emits s_load of each contiguous
// 32-float W2 row into SGPRs (K$-resident, separate scalar pipe; ~64 SMEM
// fetches/wave vs 256 ds_read_b128 in round 3 or 1024 s_load_dword/row in
// round 2). Two independent fma chains per j give ILP=2 (128 VALU cycles) to
// hide each 128 B SMEM fetch. No LDS for weights. Per-row fma chain order is
// bit-identical to rounds 2/3.
// ---------------------------------------------------------------------------
__global__ __launch_bounds__(TPB, 3) void net_main(
    const float* __restrict__ x,
    const float* __restrict__ W1, const float* __restrict__ b1,
    const float* __restrict__ W2, const float* __restrict__ b2,
    const float* __restrict__ W3, const float* __restrict__ b3,
    float* __restrict__ out,
    float* __restrict__ t_part, int* __restrict__ c_part,
    unsigned* __restrict__ counter,
    int half, int nrows, double inv_denom)
{
    const int tid = threadIdx.x;
    const int r0  = blockIdx.x * TPB + tid;

    float t_acc = 0.0f;
    int   s_cnt = 0;

    if (r0 < half) {
        const int r1 = r0 + half;
        const float2 xa = reinterpret_cast<const float2*>(x)[r0];
        const float2 xb = reinterpret_cast<const float2*>(x)[r1];

        // ---- layer 1 for both rows (weights uniform -> SGPR) ----
        float A[32], B[32];
#pragma unroll
        for (int j = 0; j < 32; ++j) {
            const float w0 = W1[2 * j], w1 = W1[2 * j + 1], bb = b1[j];
            A[j] = fmaf(xa.y, w1, fmaf(xa.x, w0, bb));
            B[j] = fmaf(xb.y, w1, fmaf(xb.x, w0, bb));
        }

        partial_act(A, t_acc, s_cnt);
        partial_act(B, t_acc, s_cnt);

        // ---- layer 2, j-outer: W2 row j is 32 contiguous floats ----
        float ZA[32], ZB[32];
#pragma unroll
        for (int j = 0; j < 32; ++j) {
            float a0 = b2[j];
            float a1 = b2[j];
#pragma unroll
            for (int k = 0; k < 32; ++k) {
                const float w = W2[32 * j + k];   // uniform -> SGPR operand
                a0 = fmaf(A[k], w, a0);           // ascending-k chain (exact
                a1 = fmaf(B[k], w, a1);           //  same order as round 2/3)
            }
            ZA[j] = a0;
            ZB[j] = a1;
        }

        partial_act(ZA, t_acc, s_cnt);
        partial_act(ZB, t_acc, s_cnt);

        // ---- layer 3 + softmax, both rows ----
        {
            float z0 = b3[0], z1 = b3[1];
            float y0 = b3[0], y1 = b3[1];
#pragma unroll
            for (int k = 0; k < 32; ++k) {
                const float wa = W3[k], wb = W3[32 + k];
                z0 = fmaf(ZA[k], wa, z0);
                z1 = fmaf(ZA[k], wb, z1);
                y0 = fmaf(ZB[k], wa, y0);
                y1 = fmaf(ZB[k], wb, y1);
            }
            float m0  = fmaxf(z0, z1);
            float e00 = __expf(z0 - m0);
            float e01 = __expf(z1 - m0);
            float i0  = 1.0f / (e00 + e01);
            float2 oa; oa.x = e00 * i0; oa.y = e01 * i0;
            reinterpret_cast<float2*>(out)[r0] = oa;

            float m1  = fmaxf(y0, y1);
            float e10 = __expf(y0 - m1);
            float e11 = __expf(y1 - m1);
            float i1  = 1.0f / (e10 + e11);
            float2 ob; ob.x = e10 * i1; ob.y = e11 * i1;
            reinterpret_cast<float2*>(out)[r1] = ob;
        }
    }

    // ---- block reduction: wave shuffle -> LDS -> per-block partial ----
#pragma unroll
    for (int off = 32; off; off >>= 1) {
        t_acc += __shfl_down(t_acc, off);
        s_cnt += __shfl_down(s_cnt, off);
    }
    __shared__ float ts[TPB / 64];
    __shared__ int   cs[TPB / 64];
    __shared__ bool  amLast;
    const int wid  = tid >> 6;
    const int lane = tid & 63;
    if (lane == 0) { ts[wid] = t_acc; cs[wid] = s_cnt; }
    __syncthreads();
    if (tid == 0) {
        float tt = ts[0];
        int   cc = cs[0];
#pragma unroll
        for (int w = 1; w < TPB / 64; ++w) { tt += ts[w]; cc += cs[w]; }
        t_part[blockIdx.x] = tt;
        c_part[blockIdx.x] = cc;
        __threadfence();                        // partials visible device-wide
        unsigned old = atomicAdd(counter, 1u);  // device-scope by default
        amLast = (old == gridDim.x - 1);
    }
    __syncthreads();

    // ---- last block reduces all partials (fixed order -> deterministic) ----
    if (amLast) {
        __threadfence();
        double t = 0.0;
        int    c = 0;
        const int nparts = gridDim.x;
        for (int i = tid; i < nparts; i += TPB) {
            t += (double)t_part[i];
            c += c_part[i];
        }
#pragma unroll
        for (int off = 32; off; off >>= 1) {
            t += __shfl_down(t, off);
            c += __shfl_down(c, off);
        }
        __shared__ double td[TPB / 64];
        __shared__ int    cd[TPB / 64];
        if (lane == 0) { td[wid] = t; cd[wid] = c; }
        __syncthreads();
        if (tid == 0) {
            double tt = 0.0;
            int    cc = 0;
#pragma unroll
            for (int w = 0; w < TPB / 64; ++w) { tt += td[w]; cc += cd[w]; }
            float* scal = out + (size_t)nrows * 2;
            scal[0] = (float)((double)cc * inv_denom); // succ = cnt / (2B)
            scal[1] = (float)tt;                       // train = t1 + t2
        }
    }
}

extern "C" void kernel_launch(void* const* d_in, const int* in_sizes, int n_in,
                              void* d_out, int out_size, void* d_ws, size_t ws_size,
                              hipStream_t stream)
{
    const float* x  = (const float*)d_in[0];
    const float* W1 = (const float*)d_in[1];
    const float* b1 = (const float*)d_in[2];
    const float* W2 = (const float*)d_in[3];
    const float* b2 = (const float*)d_in[4];
    const float* W3 = (const float*)d_in[5];
    const float* b3 = (const float*)d_in[6];
    float* out = (float*)d_out;

    const int nrows   = in_sizes[0] / 2;          // B = 1048576
    const int half    = nrows / 2;                // 2 rows per thread
    const int nblocks = (half + TPB - 1) / TPB;   // 2048

    float*    t_part  = (float*)d_ws;
    int*      c_part  = (int*)((char*)d_ws + (size_t)nblocks * sizeof(float));
    unsigned* counter = (unsigned*)((char*)d_ws + (size_t)nblocks * 2 * sizeof(float));

    // ws is poisoned 0xAA before every timed launch -> zero the done-counter.
    hipMemsetAsync(counter, 0, sizeof(unsigned), stream);

    net_main<<<nblocks, TPB, 0, stream>>>(x, W1, b1, W2, b2, W3, b3,
                                          out, t_part, c_part, counter,
                                          half, nrows, 1.0 / (2.0 * (double)nrows));
}